// Round 4
// baseline (40.965 us; speedup 1.0000x reference)
//
#include <hip/hip_runtime.h>

#define TPB   128    // nn threads per block (2 waves)
#define QPT   8      // query points per thread (registers)
#define SPLIT 32     // database slices per direction (4096/32 = 128 = one stage)
#define RTPB  256    // reduce threads per block
#define QPR   4      // queries per reduce thread (float4)

// ---------------------------------------------------------------------------
// Directed nearest-neighbor min, both directions in one launch.
//   blockIdx.z = 0 : query = pred  (NA=N), database = target (NB=M), all valid
//   blockIdx.z = 1 : query = target(NA=M), database = pred   (NB=N), label-mask
// DB staging precomputes (-2x, -2y, -2z, |t|^2), so the inner candidate is
//   v = tn - 2 p.t  via a single 3-fma chain; min over v is min over d
//   shifted by |p|^2 (added once per query at the end, clamped >= 0).
// Invalid / pad DB points: coords=0, tn=1e10  ->  candidate = pn + 1e10,
// matching the reference BIG mask to ~1e-10 relative.
// Each (tile,split) block writes its mins to a private minsplit slot: no
// atomics in the hot path, bit-deterministic.
// Also zeroes the reduce kernel's completion counter (block (0,0,0)).
// ---------------------------------------------------------------------------
__global__ void __launch_bounds__(TPB, 4) nn_kernel(
    const float* __restrict__ pred,
    const float* __restrict__ target,
    const int*   __restrict__ label,
    float* __restrict__ minsplit,     // [2][B][SPLIT][stride]
    unsigned int* __restrict__ counter,
    int B, int N, int M, int natmax, int stride)
{
    __shared__ float4 tile[TPB];

    if (blockIdx.x == 0 && blockIdx.y == 0 && blockIdx.z == 0 && threadIdx.x == 0) {
        *counter = 0u;   // consumed by reduce_kernel's last-block detection
    }

    const int dir = blockIdx.z;
    const float* __restrict__ A  = dir ? target : pred;
    const float* __restrict__ Bp = dir ? pred   : target;
    const int NA = dir ? M : N;
    const int NB = dir ? N : M;
    const int* __restrict__ labB = dir ? label : nullptr;

    const int natiles = (NA + TPB * QPT - 1) / (TPB * QPT);
    const int b  = blockIdx.x / natmax;
    const int at = blockIdx.x - b * natmax;
    if (at >= natiles) return;

    const size_t abase = (size_t)b * NA;

    float px[QPT], py[QPT], pz[QPT], pn[QPT], best[QPT];
#pragma unroll
    for (int q = 0; q < QPT; ++q) {
        int a = at * (TPB * QPT) + q * TPB + threadIdx.x;
        int idx = (a < NA) ? a : 0;
        const float* sp = A + (abase + idx) * 3;
        px[q] = sp[0];
        py[q] = sp[1];
        pz[q] = sp[2];
        pn[q] = fmaf(px[q], px[q], fmaf(py[q], py[q], pz[q] * pz[q]));
        best[q] = 3.0e38f;
    }

    const int slen = (NB + SPLIT - 1) / SPLIT;
    const int sbeg = blockIdx.y * slen;
    const int send = min(sbeg + slen, NB);
    const size_t bbase = (size_t)b * NB;

    for (int c = sbeg; c < send; c += TPB) {
        int m = c + threadIdx.x;
        float4 qv = make_float4(0.0f, 0.0f, 0.0f, 1.0e10f);  // pad sentinel
        if (m < send) {
            const float* sp = Bp + (bbase + m) * 3;
            float x = sp[0], y = sp[1], z = sp[2];
            float tn = fmaf(x, x, fmaf(y, y, z * z));
            if (labB != nullptr && labB[bbase + m] != 1) {   // invalid point
                x = 0.0f; y = 0.0f; z = 0.0f; tn = 1.0e10f;
            }
            qv = make_float4(-2.0f * x, -2.0f * y, -2.0f * z, tn);
        }
        __syncthreads();              // protect previous iteration's reads
        tile[threadIdx.x] = qv;
        __syncthreads();

        if (send - c >= TPB) {
            // full stage: compile-time trip count
#pragma unroll 8
            for (int j = 0; j < TPB; j += 2) {
                float4 t0 = tile[j];      // wave-uniform -> LDS broadcast
                float4 t1 = tile[j + 1];
#pragma unroll
                for (int q = 0; q < QPT; ++q) {
                    float v0 = fmaf(px[q], t0.x, fmaf(py[q], t0.y, fmaf(pz[q], t0.z, t0.w)));
                    float v1 = fmaf(px[q], t1.x, fmaf(py[q], t1.y, fmaf(pz[q], t1.z, t1.w)));
                    best[q] = fminf(best[q], fminf(v0, v1));   // -> v_min3_f32
                }
            }
        } else {
            int jn = send - c;
            for (int j = 0; j < jn; ++j) {
                float4 t0 = tile[j];
#pragma unroll
                for (int q = 0; q < QPT; ++q) {
                    float v0 = fmaf(px[q], t0.x, fmaf(py[q], t0.y, fmaf(pz[q], t0.z, t0.w)));
                    best[q] = fminf(best[q], v0);
                }
            }
        }
    }

    float* out = minsplit + (((size_t)dir * B + b) * SPLIT + blockIdx.y) * stride;
#pragma unroll
    for (int q = 0; q < QPT; ++q) {
        int a = at * (TPB * QPT) + q * TPB + threadIdx.x;
        if (a < NA) {
            out[a] = fmaxf(best[q] + pn[q], 0.0f);
        }
    }
}

// ---------------------------------------------------------------------------
// Reduce: per-query min over SPLIT slices (float4 loads), sqrt, masked sums,
// block reduce, then last-block final combine (device-scope atomics only).
// grid = B*(tilesN + tilesM); block r covers RTPB*QPR queries of one (dir,b).
// ---------------------------------------------------------------------------
__device__ __forceinline__ float block_reduce_sum(float v, float* red) {
    int tid = threadIdx.x;
    red[tid] = v;
    __syncthreads();
    for (int s = RTPB / 2; s > 0; s >>= 1) {
        if (tid < s) red[tid] += red[tid + s];
        __syncthreads();
    }
    float r = red[0];
    __syncthreads();
    return r;
}

__global__ void __launch_bounds__(RTPB) reduce_kernel(
    const float* __restrict__ minsplit,
    const int* __restrict__ label,
    float* __restrict__ pS, float* __restrict__ pC,
    unsigned int* __restrict__ counter,
    float* __restrict__ out,
    int B, int N, int M, int tilesN, int tilesM, int stride, int nblocks)
{
    __shared__ float red[RTPB];
    const int r = blockIdx.x;

    int dir, b, t, NA;
    if (r < B * tilesN) { dir = 0; b = r / tilesN; t = r - b * tilesN; NA = N; }
    else { int r2 = r - B * tilesN; dir = 1; b = r2 / tilesM; t = r2 - b * tilesM; NA = M; }

    const float* base = minsplit + (((size_t)dir * B + b) * SPLIT) * stride;
    const int q0 = t * (RTPB * QPR) + threadIdx.x * QPR;

    float s = 0.0f, cc = 0.0f;
    if (q0 + QPR <= NA) {
        float4 mv = *reinterpret_cast<const float4*>(base + q0);
#pragma unroll 8
        for (int sp = 1; sp < SPLIT; ++sp) {
            float4 v = *reinterpret_cast<const float4*>(base + (size_t)sp * stride + q0);
            mv.x = fminf(mv.x, v.x);
            mv.y = fminf(mv.y, v.y);
            mv.z = fminf(mv.z, v.z);
            mv.w = fminf(mv.w, v.w);
        }
        if (dir == 0) {
            int4 lb = *reinterpret_cast<const int4*>(label + (size_t)b * N + q0);
            if (lb.x == 1) { s += sqrtf(mv.x); cc += 1.0f; }
            if (lb.y == 1) { s += sqrtf(mv.y); cc += 1.0f; }
            if (lb.z == 1) { s += sqrtf(mv.z); cc += 1.0f; }
            if (lb.w == 1) { s += sqrtf(mv.w); cc += 1.0f; }
        } else {
            s = sqrtf(mv.x) + sqrtf(mv.y) + sqrtf(mv.z) + sqrtf(mv.w);
        }
    } else {
        for (int k = 0; k < QPR; ++k) {
            int q = q0 + k;
            if (q < NA) {
                float m = base[q];
                for (int sp = 1; sp < SPLIT; ++sp) {
                    m = fminf(m, base[(size_t)sp * stride + q]);
                }
                if (dir == 0) {
                    if (label[(size_t)b * N + q] == 1) { s += sqrtf(m); cc += 1.0f; }
                } else {
                    s += sqrtf(m);
                }
            }
        }
    }

    s = block_reduce_sum(s, red);
    if (dir == 0) cc = block_reduce_sum(cc, red);

    if (threadIdx.x == 0) {
        atomicExch(&pS[r], s);                 // device-scope, XCD-coherent
        atomicExch(&pC[r], cc);
        __threadfence();
        unsigned int old = atomicAdd(counter, 1u);
        if (old == (unsigned int)(nblocks - 1)) {
            // last block: fixed-order combine (deterministic regardless of
            // which block arrives last)
            float acc = 0.0f;
            for (int bb = 0; bb < B; ++bb) {
                float S1 = 0.0f, C1 = 0.0f, S2 = 0.0f;
                for (int i = 0; i < tilesN; ++i) {
                    S1 += atomicAdd(&pS[bb * tilesN + i], 0.0f);
                    C1 += atomicAdd(&pC[bb * tilesN + i], 0.0f);
                }
                for (int i = 0; i < tilesM; ++i) {
                    S2 += atomicAdd(&pS[B * tilesN + bb * tilesM + i], 0.0f);
                }
                float m1 = S1 / fmaxf(C1, 1.0f);
                float m2 = S2 / (float)M;
                acc += 0.5f * (m1 + m2);
            }
            out[0] = acc / (float)B;   // * LOSS_WEIGHT (== 1.0)
        }
    }
}

// ---------------------------------------------------------------------------
extern "C" void kernel_launch(void* const* d_in, const int* in_sizes, int n_in,
                              void* d_out, int out_size, void* d_ws, size_t ws_size,
                              hipStream_t stream) {
    const float* pred   = (const float*)d_in[0];  // B*N*3 f32
    const float* target = (const float*)d_in[1];  // B*M*3 f32
    const int*   label  = (const int*)  d_in[2];  // B*N   i32

    const int B = in_sizes[3];                 // nums has shape (B,)
    const int N = in_sizes[2] / B;             // label is B*N
    const int M = in_sizes[1] / (3 * B);       // target is B*M*3

    const int stride = (N > M) ? N : M;

    // workspace layout (~4.2 MiB of the provided scratch)
    float* minsplit = (float*)d_ws;                               // 2*B*SPLIT*stride
    const int tilesN = (N + RTPB * QPR - 1) / (RTPB * QPR);
    const int tilesM = (M + RTPB * QPR - 1) / (RTPB * QPR);
    const int nred = B * (tilesN + tilesM);
    float* pS = minsplit + (size_t)2 * B * SPLIT * stride;        // nred
    float* pC = pS + nred;                                        // nred
    unsigned int* counter = (unsigned int*)(pC + nred);

    const int nat1 = (N + TPB * QPT - 1) / (TPB * QPT);
    const int nat2 = (M + TPB * QPT - 1) / (TPB * QPT);
    const int natmax = (nat1 > nat2) ? nat1 : nat2;
    dim3 g(B * natmax, SPLIT, 2);
    nn_kernel<<<g, TPB, 0, stream>>>(pred, target, label, minsplit, counter,
                                     B, N, M, natmax, stride);

    reduce_kernel<<<nred, RTPB, 0, stream>>>(minsplit, label, pS, pC, counter,
                                             (float*)d_out,
                                             B, N, M, tilesN, tilesM, stride, nred);
}